// Round 8
// baseline (25.722 us; speedup 1.0000x reference)
//
#include <hip/hip_runtime.h>

// Problem constants (match reference setup_inputs)
#define BATCH 2
#define NPART 4096
#define TI 256                  // threads per block
#define IPT 4                   // i-particles per thread (amortizes j-broadcasts)
#define ITILE (TI * IPT)        // 1024 i per block
#define NITILES (NPART / ITILE) // 4
#define JSEGS 128               // -> 128*4*2 = 1024 blocks (4/CU, 4 waves/SIMD)
#define SEG (NPART / JSEGS)     // 32 j-particles staged in LDS per block
#define PLANE (BATCH * NPART)   // 8192 floats per (jseg,c) partial plane

typedef float v2f __attribute__((ext_vector_type(2)));

// Inner loop: IPT i's per thread x 2 j's per iteration (packed f32).
// One broadcast j-load feeds IPT*2 = 8 pairs -> LDS pipe ~40% of VALU window.
// Per-element v_rcp keeps the chain short. MASKED=true only for diagonal blocks.
template <bool MASKED>
__device__ inline void lj_inner(const v2f* __restrict__ xs, const v2f* __restrict__ ys,
                                const v2f* __restrict__ zs,
                                const float* qx, const float* qy, const float* qz,
                                v2f* fx, v2f* fy, v2f* fz) {
    #pragma unroll 2
    for (int jj = 0; jj < SEG / 2; ++jj) {
        const v2f jx = xs[jj];
        const v2f jy = ys[jj];
        const v2f jz = zs[jj];
        #pragma unroll
        for (int k = 0; k < IPT; ++k) {
            const v2f dx = (v2f)qx[k] - jx;
            const v2f dy = (v2f)qy[k] - jy;
            const v2f dz = (v2f)qz[k] - jz;
            v2f r2 = dx * dx;
            r2 = __builtin_elementwise_fma(dy, dy, r2);
            r2 = __builtin_elementwise_fma(dz, dz, r2);

            // approximate reciprocal; r2==0.0f exactly <=> i==j (reference's mask)
            v2f inv;
            inv.x = __builtin_amdgcn_rcpf(r2.x);
            inv.y = __builtin_amdgcn_rcpf(r2.y);
            if (MASKED) {
                inv.x = (r2.x > 0.0f) ? inv.x : 0.0f;
                inv.y = (r2.y > 0.0f) ? inv.y : 0.0f;
            }
            const v2f inv2 = inv * inv;
            const v2f s6 = inv2 * inv;                                   // sigma = 1
            const v2f c1 = __builtin_elementwise_fma((v2f)48.0f, s6, (v2f)(-24.0f));
            const v2f coeff = (inv * s6) * c1;    // 24*inv*s6*(2*s6-1)
            fx[k] = __builtin_elementwise_fma(coeff, dx, fx[k]);
            fy[k] = __builtin_elementwise_fma(coeff, dy, fy[k]);
            fz[k] = __builtin_elementwise_fma(coeff, dz, fz[k]);
        }
    }
}

// Grid: (JSEGS, NITILES, BATCH), block TI=256.
// Plain coalesced stores of per-jseg partials (no atomics, no memset):
//   ws[(jseg*3 + c) * PLANE + b*NPART + i]
__global__ __launch_bounds__(256) void lj_kernel(const float* __restrict__ q,
                                                 float* __restrict__ ws) {
    __shared__ float qsx[SEG], qsy[SEG], qsz[SEG];

    const int jseg  = blockIdx.x;
    const int itile = blockIdx.y;
    const int b     = blockIdx.z;

    const float* qb = q + (size_t)b * NPART * 3;

    if (threadIdx.x < SEG) {
        const int k = threadIdx.x;
        const int jb = (jseg * SEG + k) * 3;
        qsx[k] = qb[jb + 0];
        qsy[k] = qb[jb + 1];
        qsz[k] = qb[jb + 2];
    }
    __syncthreads();

    const int i0 = itile * ITILE + threadIdx.x;
    float qx[IPT], qy[IPT], qz[IPT];
    #pragma unroll
    for (int k = 0; k < IPT; ++k) {
        const int i = i0 + k * TI;
        qx[k] = qb[i * 3 + 0];
        qy[k] = qb[i * 3 + 1];
        qz[k] = qb[i * 3 + 2];
    }

    v2f fx[IPT], fy[IPT], fz[IPT];
    #pragma unroll
    for (int k = 0; k < IPT; ++k) { fx[k] = (v2f)0.0f; fy[k] = (v2f)0.0f; fz[k] = (v2f)0.0f; }

    // Diagonal possible iff j-range within this block's i-range (ITILE/SEG = 32)
    if ((jseg >> 5) == itile) {
        lj_inner<true >((const v2f*)qsx, (const v2f*)qsy, (const v2f*)qsz,
                        qx, qy, qz, fx, fy, fz);
    } else {
        lj_inner<false>((const v2f*)qsx, (const v2f*)qsy, (const v2f*)qsz,
                        qx, qy, qz, fx, fy, fz);
    }

    const size_t wbase = (size_t)(jseg * 3) * PLANE + (size_t)b * NPART;
    #pragma unroll
    for (int k = 0; k < IPT; ++k) {
        const int i = i0 + k * TI;
        ws[wbase + i]             = fx[k].x + fx[k].y;
        ws[wbase + PLANE + i]     = fy[k].x + fy[k].y;
        ws[wbase + 2 * PLANE + i] = fz[k].x + fz[k].y;
    }
}

// Sum 128 per-jseg partials per dp element (L2-resident, coalesced across bi);
// fuse dq = p/m. o in [0, 24576) maps to (c, b*NPART+i).
__global__ __launch_bounds__(256) void reduce_kernel(const float* __restrict__ ws,
                                                     const float* __restrict__ p,
                                                     const float* __restrict__ m,
                                                     float* __restrict__ dq,
                                                     float* __restrict__ dp) {
    const int o  = blockIdx.x * 256 + threadIdx.x;   // 24576 threads, 96 blocks
    const int c  = o >> 13;          // / PLANE
    const int bi = o & (PLANE - 1);  // b*NPART + i

    float s0 = 0.0f, s1 = 0.0f, s2 = 0.0f, s3 = 0.0f;
    float s4 = 0.0f, s5 = 0.0f, s6 = 0.0f, s7 = 0.0f;
    #pragma unroll
    for (int js = 0; js < JSEGS; js += 8) {
        s0 += ws[(size_t)((js + 0) * 3 + c) * PLANE + bi];
        s1 += ws[(size_t)((js + 1) * 3 + c) * PLANE + bi];
        s2 += ws[(size_t)((js + 2) * 3 + c) * PLANE + bi];
        s3 += ws[(size_t)((js + 3) * 3 + c) * PLANE + bi];
        s4 += ws[(size_t)((js + 4) * 3 + c) * PLANE + bi];
        s5 += ws[(size_t)((js + 5) * 3 + c) * PLANE + bi];
        s6 += ws[(size_t)((js + 6) * 3 + c) * PLANE + bi];
        s7 += ws[(size_t)((js + 7) * 3 + c) * PLANE + bi];
    }
    dp[(size_t)bi * 3 + c] = ((s0 + s1) + (s2 + s3)) + ((s4 + s5) + (s6 + s7));

    // dq = p/m for flat element o (exact IEEE div, only 24576 of them)
    dq[o] = p[o] / m[o / 3];
}

extern "C" void kernel_launch(void* const* d_in, const int* in_sizes, int n_in,
                              void* d_out, int out_size, void* d_ws, size_t ws_size,
                              hipStream_t stream) {
    const float* q = (const float*)d_in[0];
    const float* p = (const float*)d_in[1];
    const float* m = (const float*)d_in[2];
    // d_in[3] = t, unused by the reference outputs

    const int n_elem = BATCH * NPART * 3;   // 24576 per output tensor
    float* dq_out = (float*)d_out;          // first output: dq
    float* dp_out = (float*)d_out + n_elem; // second output: dp
    float* ws     = (float*)d_ws;           // 128*3*8192 floats = 12.6 MB partials

    dim3 grid(JSEGS, NITILES, BATCH);
    lj_kernel<<<grid, TI, 0, stream>>>(q, ws);

    reduce_kernel<<<n_elem / 256, 256, 0, stream>>>(ws, p, m, dq_out, dp_out);
}

// Round 9
// 23.088 us; speedup vs baseline: 1.1141x; 1.1141x over previous
//
#include <hip/hip_runtime.h>

// Problem constants (match reference setup_inputs)
#define BATCH 2
#define NPART 4096
#define TI 256                  // threads per block
#define IPT 4                   // i-particles per thread (2 packed v2f chains)
#define ITILE (TI * IPT)        // 1024 i per block
#define NITILES (NPART / ITILE) // 4
#define JSEGS 64                // -> 64*4*2 = 512 blocks (2/CU), ws = 6.3 MB
#define SEG (NPART / JSEGS)     // 64 j-particles per block (scalar-cache loads)
#define PLANE (BATCH * NPART)   // 8192 floats per (jseg,c) partial plane

typedef float v2f __attribute__((ext_vector_type(2)));

// Inner loop: j is block-uniform -> j coords come in via s_load (scalar cache,
// no LDS, no vector VMEM, no syncthreads). v2f packs 2 i's per instruction.
// MASKED=true only for blocks whose j-range overlaps their i-range.
template <bool MASKED>
__device__ inline void lj_inner(const float* __restrict__ jq,
                                const v2f* qx, const v2f* qy, const v2f* qz,
                                v2f* fx, v2f* fy, v2f* fz) {
    #pragma unroll 8
    for (int j = 0; j < SEG; ++j) {
        const float jx = jq[3 * j + 0];   // uniform -> SGPR
        const float jy = jq[3 * j + 1];
        const float jz = jq[3 * j + 2];
        #pragma unroll
        for (int k = 0; k < IPT / 2; ++k) {
            const v2f dx = qx[k] - (v2f)jx;
            const v2f dy = qy[k] - (v2f)jy;
            const v2f dz = qz[k] - (v2f)jz;
            v2f r2 = dx * dx;
            r2 = __builtin_elementwise_fma(dy, dy, r2);
            r2 = __builtin_elementwise_fma(dz, dz, r2);

            // approximate reciprocal; r2==0.0f exactly <=> i==j (reference mask)
            v2f inv;
            inv.x = __builtin_amdgcn_rcpf(r2.x);
            inv.y = __builtin_amdgcn_rcpf(r2.y);
            if (MASKED) {
                inv.x = (r2.x > 0.0f) ? inv.x : 0.0f;
                inv.y = (r2.y > 0.0f) ? inv.y : 0.0f;
            }
            const v2f inv2 = inv * inv;
            const v2f s6 = inv2 * inv;                                   // sigma = 1
            const v2f c1 = __builtin_elementwise_fma((v2f)48.0f, s6, (v2f)(-24.0f));
            const v2f coeff = (inv * s6) * c1;    // 24*inv*s6*(2*s6-1)
            fx[k] = __builtin_elementwise_fma(coeff, dx, fx[k]);
            fy[k] = __builtin_elementwise_fma(coeff, dy, fy[k]);
            fz[k] = __builtin_elementwise_fma(coeff, dz, fz[k]);
        }
    }
}

// Grid: (JSEGS, NITILES, BATCH), block TI=256. No LDS, no atomics, no memset.
// Coalesced stores of per-jseg partials: ws[(jseg*3 + c)*PLANE + b*NPART + i]
__global__ __launch_bounds__(256) void lj_kernel(const float* __restrict__ q,
                                                 float* __restrict__ ws) {
    const int jseg  = blockIdx.x;
    const int itile = blockIdx.y;
    const int b     = blockIdx.z;

    const float* qb = q + (size_t)b * NPART * 3;
    const float* jq = qb + jseg * SEG * 3;

    const int i0 = itile * ITILE + threadIdx.x;

    v2f qx[IPT / 2], qy[IPT / 2], qz[IPT / 2];
    v2f fx[IPT / 2], fy[IPT / 2], fz[IPT / 2];
    #pragma unroll
    for (int k = 0; k < IPT / 2; ++k) {
        const int ia = i0 + (2 * k) * TI;
        const int ib = i0 + (2 * k + 1) * TI;
        qx[k] = (v2f){qb[ia * 3 + 0], qb[ib * 3 + 0]};
        qy[k] = (v2f){qb[ia * 3 + 1], qb[ib * 3 + 1]};
        qz[k] = (v2f){qb[ia * 3 + 2], qb[ib * 3 + 2]};
        fx[k] = (v2f)0.0f; fy[k] = (v2f)0.0f; fz[k] = (v2f)0.0f;
    }

    // Diagonal possible iff j-range within this block's i-range (ITILE/SEG = 16)
    if ((jseg >> 4) == itile) {
        lj_inner<true >(jq, qx, qy, qz, fx, fy, fz);
    } else {
        lj_inner<false>(jq, qx, qy, qz, fx, fy, fz);
    }

    const size_t wbase = (size_t)(jseg * 3) * PLANE + (size_t)b * NPART;
    #pragma unroll
    for (int k = 0; k < IPT / 2; ++k) {
        const int ia = i0 + (2 * k) * TI;
        const int ib = i0 + (2 * k + 1) * TI;
        ws[wbase + ia]             = fx[k].x;  ws[wbase + ib]             = fx[k].y;
        ws[wbase + PLANE + ia]     = fy[k].x;  ws[wbase + PLANE + ib]     = fy[k].y;
        ws[wbase + 2 * PLANE + ia] = fz[k].x;  ws[wbase + 2 * PLANE + ib] = fz[k].y;
    }
}

// Sum 64 per-jseg partials per dp element (L2-resident, coalesced across bi);
// fuse dq = p/m. o in [0, 24576) maps to (c, b*NPART+i).
__global__ __launch_bounds__(256) void reduce_kernel(const float* __restrict__ ws,
                                                     const float* __restrict__ p,
                                                     const float* __restrict__ m,
                                                     float* __restrict__ dq,
                                                     float* __restrict__ dp) {
    const int o  = blockIdx.x * 256 + threadIdx.x;   // 24576 threads, 96 blocks
    const int c  = o >> 13;          // / PLANE
    const int bi = o & (PLANE - 1);  // b*NPART + i

    float s0 = 0.0f, s1 = 0.0f, s2 = 0.0f, s3 = 0.0f;
    float s4 = 0.0f, s5 = 0.0f, s6 = 0.0f, s7 = 0.0f;
    #pragma unroll
    for (int js = 0; js < JSEGS; js += 8) {
        s0 += ws[(size_t)((js + 0) * 3 + c) * PLANE + bi];
        s1 += ws[(size_t)((js + 1) * 3 + c) * PLANE + bi];
        s2 += ws[(size_t)((js + 2) * 3 + c) * PLANE + bi];
        s3 += ws[(size_t)((js + 3) * 3 + c) * PLANE + bi];
        s4 += ws[(size_t)((js + 4) * 3 + c) * PLANE + bi];
        s5 += ws[(size_t)((js + 5) * 3 + c) * PLANE + bi];
        s6 += ws[(size_t)((js + 6) * 3 + c) * PLANE + bi];
        s7 += ws[(size_t)((js + 7) * 3 + c) * PLANE + bi];
    }
    dp[(size_t)bi * 3 + c] = ((s0 + s1) + (s2 + s3)) + ((s4 + s5) + (s6 + s7));

    // dq = p/m for flat element o (exact IEEE div, only 24576 of them)
    dq[o] = p[o] / m[o / 3];
}

extern "C" void kernel_launch(void* const* d_in, const int* in_sizes, int n_in,
                              void* d_out, int out_size, void* d_ws, size_t ws_size,
                              hipStream_t stream) {
    const float* q = (const float*)d_in[0];
    const float* p = (const float*)d_in[1];
    const float* m = (const float*)d_in[2];
    // d_in[3] = t, unused by the reference outputs

    const int n_elem = BATCH * NPART * 3;   // 24576 per output tensor
    float* dq_out = (float*)d_out;          // first output: dq
    float* dp_out = (float*)d_out + n_elem; // second output: dp
    float* ws     = (float*)d_ws;           // 64*3*8192 floats = 6.3 MB partials

    dim3 grid(JSEGS, NITILES, BATCH);
    lj_kernel<<<grid, TI, 0, stream>>>(q, ws);

    reduce_kernel<<<n_elem / 256, 256, 0, stream>>>(ws, p, m, dq_out, dp_out);
}

// Round 10
// 19.092 us; speedup vs baseline: 1.3473x; 1.2093x over previous
//
#include <hip/hip_runtime.h>

// Problem constants (match reference setup_inputs)
#define BATCH    2
#define NPART    4096
#define NTHREADS 512
#define IBLK     16                   // i per block
#define ILANES   8                    // lane slots in i-dim (2 i packed per lane)
#define JCH      (NTHREADS / ILANES)  // 64 j-chunks per block
#define JLEN     (NPART / JCH)        // 64 j per chunk
#define NIB      (NPART / IBLK)       // 256 i-blocks per batch

typedef float v2f __attribute__((ext_vector_type(2)));

// Fully fused: one kernel computes dp AND dq. Each block owns 16 i's and the
// ENTIRE j range (split into 64 chunks across thread groups); j-partials are
// reduced in LDS. No workspace, no second dispatch, no atomics, no memset.
// v2f packs the TWO i's per lane, so j enters as scalar splats (no shuffles).
__global__ __launch_bounds__(NTHREADS, 4) void lj_fused(
        const float* __restrict__ q, const float* __restrict__ p,
        const float* __restrict__ m, float* __restrict__ dq,
        float* __restrict__ dp) {
    // red[(k*6 + (c*2+h)) * ILANES + il]  -> reduce-reads conflict-free
    __shared__ float red[JCH * 6 * ILANES];   // 12 KB

    const int ib = blockIdx.x;
    const int b  = blockIdx.y;
    const int t  = threadIdx.x;
    const int il = t & (ILANES - 1);
    const int jc = t >> 3;                    // 0..63

    const float* qb = q + (size_t)b * NPART * 3;

    const int i0 = ib * IBLK + il;            // first i of this lane
    const int i1 = i0 + ILANES;               // second i of this lane
    const v2f qx = {qb[i0 * 3 + 0], qb[i1 * 3 + 0]};
    const v2f qy = {qb[i0 * 3 + 1], qb[i1 * 3 + 1]};
    const v2f qz = {qb[i0 * 3 + 2], qb[i1 * 3 + 2]};

    v2f fx = (v2f)0.0f, fy = (v2f)0.0f, fz = (v2f)0.0f;

    // This chunk's 64 j's = 192 floats = 48 float4, 16B-aligned.
    const float4* jq4 = (const float4*)(qb + (size_t)jc * JLEN * 3);

    #pragma unroll 2
    for (int it = 0; it < JLEN / 4; ++it) {
        const float4 A = jq4[3 * it + 0];   // x0 y0 z0 x1
        const float4 B = jq4[3 * it + 1];   // y1 z1 x2 y2
        const float4 C = jq4[3 * it + 2];   // z2 x3 y3 z3
        const float jxs[4] = {A.x, A.w, B.z, C.y};
        const float jys[4] = {A.y, B.x, B.w, C.z};
        const float jzs[4] = {A.z, B.y, C.x, C.w};
        #pragma unroll
        for (int u = 0; u < 4; ++u) {
            const v2f dx = qx - (v2f)jxs[u];   // packed over the 2 i's
            const v2f dy = qy - (v2f)jys[u];
            const v2f dz = qz - (v2f)jzs[u];
            v2f r2 = dx * dx;
            r2 = __builtin_elementwise_fma(dy, dy, r2);
            r2 = __builtin_elementwise_fma(dz, dz, r2);
            // r2 == 0.0f exactly <=> i == j (reference's mask semantics)
            v2f inv;
            inv.x = (r2.x > 0.0f) ? __builtin_amdgcn_rcpf(r2.x) : 0.0f;
            inv.y = (r2.y > 0.0f) ? __builtin_amdgcn_rcpf(r2.y) : 0.0f;
            const v2f inv2 = inv * inv;
            const v2f s6 = inv2 * inv;                                    // sigma=1
            const v2f c1 = __builtin_elementwise_fma((v2f)48.0f, s6, (v2f)(-24.0f));
            const v2f coeff = (inv * s6) * c1;    // 24*inv*s6*(2*s6-1)
            fx = __builtin_elementwise_fma(coeff, dx, fx);
            fy = __builtin_elementwise_fma(coeff, dy, fy);
            fz = __builtin_elementwise_fma(coeff, dz, fz);
        }
    }

    // Stash this thread's 6 partials (2 i-halves x 3 components)
    red[(jc * 6 + 0) * ILANES + il] = fx.x;
    red[(jc * 6 + 1) * ILANES + il] = fx.y;
    red[(jc * 6 + 2) * ILANES + il] = fy.x;
    red[(jc * 6 + 3) * ILANES + il] = fy.y;
    red[(jc * 6 + 4) * ILANES + il] = fz.x;
    red[(jc * 6 + 5) * ILANES + il] = fz.y;
    __syncthreads();

    // 48 threads: one per (c, i-in-block). Sum 64 chunk partials, store dp;
    // fuse dq = p/m for the same (i, c).
    if (t < 48) {
        const int c   = t >> 4;        // 0..2
        const int ii  = t & 15;        // 0..15
        const int h   = ii >> 3;       // which packed half
        const int il2 = ii & 7;
        const int slot = c * 2 + h;
        float s = 0.0f;
        #pragma unroll
        for (int k = 0; k < JCH; ++k) {
            s += red[(k * 6 + slot) * ILANES + il2];
        }
        const size_t gi = (size_t)b * NPART + ib * IBLK + ii;
        dp[gi * 3 + c] = s;
        dq[gi * 3 + c] = p[gi * 3 + c] / m[gi];   // exact IEEE div, tiny count
    }
}

extern "C" void kernel_launch(void* const* d_in, const int* in_sizes, int n_in,
                              void* d_out, int out_size, void* d_ws, size_t ws_size,
                              hipStream_t stream) {
    const float* q = (const float*)d_in[0];
    const float* p = (const float*)d_in[1];
    const float* m = (const float*)d_in[2];
    // d_in[3] = t, unused by the reference outputs

    const int n_elem = BATCH * NPART * 3;   // 24576 per output tensor
    float* dq_out = (float*)d_out;          // first output: dq
    float* dp_out = (float*)d_out + n_elem; // second output: dp

    dim3 grid(NIB, BATCH);                  // 512 blocks x 512 threads
    lj_fused<<<grid, NTHREADS, 0, stream>>>(q, p, m, dq_out, dp_out);
}